// Round 15
// baseline (170.697 us; speedup 1.0000x reference)
//
#include <hip/hip_runtime.h>
#include <math.h>

#define BB 16
#define LL 1024
#define DM 6
#define NST 32
#define DCONVK 16
#define NCLS 4
#define CH 64    // positions per pre-kernel block
#define HALO 15
#define ROWS (CH + HALO)   // 79
#define PBT 1024           // pre block threads
#define SNC 32   // scan chunks per block
#define SCS 32   // scan chunk length (SNC*SCS = LL)

__device__ __forceinline__ float softplus_f(float x) {
    return fmaxf(x, 0.f) + log1pf(expf(-fabsf(x)));
}
__device__ __forceinline__ float silu_f(float x) {
    return x / (1.f + __expf(-x));
}

// ---- pre (unchanged from R14 best) ----
template<int MODE>
__global__ __launch_bounds__(PBT) void pre_kernel(
    const float* __restrict__ hin,     // x (B,L,6): MODE0 input / MODE1 residual
    const float* __restrict__ ygT_in,  // MODE1: (B,48,L)
    const float* __restrict__ opw,     // MODE1: (48,6)
    const float* __restrict__ ipw,     // (6,96)
    const float* __restrict__ nw,      // (6)
    const float* __restrict__ cw,      // (48,16)
    const float* __restrict__ cb,      // (48)
    const float* __restrict__ xpw,     // (48,65)
    const float* __restrict__ dtw,     // (48)
    const float* __restrict__ dtb,     // (48)
    float* __restrict__ xT,            // (B,48,L)
    float* __restrict__ zT,            // (B,48,L)  silu-applied
    float* __restrict__ dT,            // (B,48,L)
    float* __restrict__ Bi4,           // (B,L/4,32,4)
    float* __restrict__ Ci4,           // (B,L/4,32,4)
    float* __restrict__ CT)            // (B,32,L)
{
    __shared__ float s_un[ROWS*49 > 64*(CH+1) ? ROWS*49 : 64*(CH+1)];
    __shared__ float s_ipw[6*96];
    __shared__ float s_nw[8];
    __shared__ float s_cw[48*DCONVK];
    __shared__ float s_cb[48];
    __shared__ float s_xpw[48*65];
    __shared__ float s_dtw[48];
    __shared__ float s_dtb[48];
    __shared__ float s_opw[48*6];
    __shared__ float s_u[ROWS*7];
    __shared__ float s_xsT[48*CH];        // [c][p] channel-major
    __shared__ float s_dlt[CH];

    float* s_pp  = s_un;   // MODE1 phase 0: (ROWS,8,6)
    float* s_raw = s_un;   // phase 1-2: (ROWS,49)
    float* s_bc  = s_un;   // phase 3-3b: (64, CH+1)

    const int tid = threadIdx.x;
    const int b  = blockIdx.x >> 4;
    const int l0 = (blockIdx.x & 15) * CH;

    for (int i = tid; i < 6*96; i += PBT) s_ipw[i] = ipw[i];
    if (tid < 6) s_nw[tid] = nw[tid];
    if (tid < 48*DCONVK) s_cw[tid] = cw[tid];
    if (tid < 48) s_cb[tid] = cb[tid];
    for (int i = tid; i < 48*65; i += PBT) s_xpw[i] = xpw[i];
    if (tid < 48) { s_dtw[tid] = dtw[tid]; s_dtb[tid] = dtb[tid]; }
    if (MODE == 1) { if (tid < 48*6) s_opw[tid] = opw[tid]; }
    __syncthreads();

    // ---- phase 0: produce s_u (normalized rows l0-15 .. l0+CH-1) ----
    if (MODE == 0) {
        if (tid < ROWS) {
            int l = l0 - HALO + tid;
            float u[DM];
            if (l >= 0) {
                float ss = 0.f;
                const float* hp = hin + ((size_t)b*LL + l)*DM;
                #pragma unroll
                for (int d = 0; d < DM; ++d) { u[d] = hp[d]; ss += u[d]*u[d]; }
                float sc = rsqrtf(ss * (1.f/DM) + 1e-5f);
                #pragma unroll
                for (int d = 0; d < DM; ++d) u[d] *= sc * s_nw[d];
            } else {
                #pragma unroll
                for (int d = 0; d < DM; ++d) u[d] = 0.f;
            }
            #pragma unroll
            for (int d = 0; d < DM; ++d) s_u[tid*7+d] = u[d];
        }
        __syncthreads();
    } else {
        const int g = tid >> 7, t = tid & 127;   // 8 groups x 128 rows
        if (t < ROWS) {
            int l = l0 - HALO + t;
            float pacc[DM] = {0,0,0,0,0,0};
            if (l >= 0) {
                for (int e = g*6; e < g*6 + 6; ++e) {
                    float v = ygT_in[((size_t)b*48 + e)*LL + l];
                    #pragma unroll
                    for (int d = 0; d < DM; ++d) pacc[d] += v * s_opw[e*DM+d];
                }
            }
            #pragma unroll
            for (int d = 0; d < DM; ++d) s_pp[(t*8+g)*DM+d] = pacc[d];
        }
        __syncthreads();
        float u[DM]; float ss = 0.f;
        if (tid < ROWS) {
            int l = l0 - HALO + tid;
            if (l >= 0) {
                const float* xr = hin + ((size_t)b*LL + l)*DM;
                #pragma unroll
                for (int d = 0; d < DM; ++d) {
                    float hv = xr[d];
                    #pragma unroll
                    for (int g2 = 0; g2 < 8; ++g2) hv += s_pp[(tid*8+g2)*DM+d];
                    u[d] = hv; ss += hv*hv;
                }
                float sc = rsqrtf(ss * (1.f/DM) + 1e-5f);
                #pragma unroll
                for (int d = 0; d < DM; ++d) u[d] *= sc * s_nw[d];
            } else {
                #pragma unroll
                for (int d = 0; d < DM; ++d) u[d] = 0.f;
            }
        }
        __syncthreads();   // s_pp dead before s_raw written (same memory)
        if (tid < ROWS) {
            #pragma unroll
            for (int d = 0; d < DM; ++d) s_u[tid*7+d] = u[d];
        }
        __syncthreads();
    }

    // ---- phase 1: in_proj (96 cols x ROWS rows); z gets silu applied ----
    for (int i = tid; i < 96*ROWS; i += PBT) {
        int j = i / ROWS, t = i - j*ROWS;
        float acc = 0.f;
        #pragma unroll
        for (int d = 0; d < DM; ++d) acc += s_u[t*7+d]*s_ipw[d*96+j];
        if (j < 48) s_raw[t*49+j] = acc;
        else if (t >= HALO)
            zT[((size_t)b*48 + (j-48))*LL + (l0 - HALO + t)] = silu_f(acc);
    }
    __syncthreads();

    // ---- phase 2: depthwise causal conv (K=16) + silu ----
    for (int o = tid; o < 48*CH; o += PBT) {
        int c = o >> 6, p = o & 63;
        float acc = s_cb[c];
        #pragma unroll
        for (int k = 0; k < DCONVK; ++k)
            acc += s_raw[(p+k)*49 + c] * s_cw[c*DCONVK + k];
        float v = silu_f(acc);
        s_xsT[c*CH + p] = v;
        xT[((size_t)b*48 + c)*LL + l0 + p] = v;
    }
    __syncthreads();   // s_raw dead before s_bc written (same memory)

    // ---- phase 3: x_proj. thread = (col j:64, pos-group g:16), 4 pos each ----
    {
        const int j = tid >> 4, g = tid & 15;
        float a0=0,a1=0,a2=0,a3=0;
        for (int e = 0; e < 48; ++e) {
            float4 xv = *(const float4*)&s_xsT[e*CH + 4*g];
            float w = s_xpw[e*65 + 1 + j];
            a0 = fmaf(xv.x, w, a0); a1 = fmaf(xv.y, w, a1);
            a2 = fmaf(xv.z, w, a2); a3 = fmaf(xv.w, w, a3);
        }
        s_bc[j*(CH+1) + 4*g+0] = a0; s_bc[j*(CH+1) + 4*g+1] = a1;
        s_bc[j*(CH+1) + 4*g+2] = a2; s_bc[j*(CH+1) + 4*g+3] = a3;
    }
    if (tid < CH) {
        float acc = 0.f;
        for (int e = 0; e < 48; ++e) acc += s_xsT[e*CH + tid]*s_xpw[e*65];
        s_dlt[tid] = acc;
    }
    __syncthreads();

    // ---- phase 3b: write B/C packed (B,L/4,32,4) + C transposed ----
    {   // 2*(CH/4)*32 = 1024 items, exactly one per thread
        int o = tid;
        int which = o >> 9;                 // 0:B 1:C
        int lg = (o >> 5) & (CH/4 - 1), n = o & 31;
        const float* src = &s_bc[(which*32 + n)*(CH+1) + 4*lg];
        float4 v = make_float4(src[0], src[1], src[2], src[3]);
        float4* dst = (float4*)(which ? Ci4 : Bi4);
        dst[((size_t)b*(LL/4) + (l0/4 + lg))*32 + n] = v;
    }
    for (int o = tid; o < 32*CH; o += PBT) {
        int n = o >> 6, l = o & 63;
        CT[((size_t)b*32 + n)*LL + l0 + l] = s_bc[(32+n)*(CH+1) + l];
    }

    // ---- phase 4: delta = softplus(dlt*dt_w + dt_b), transposed write ----
    for (int o = tid; o < 48*CH; o += PBT) {
        int e = o >> 6, p = o & 63;
        float xv = s_dlt[p]*s_dtw[e] + s_dtb[e];
        dT[((size_t)b*48 + e)*LL + l0 + p] = softplus_f(xv);
    }
}

// ---- fused selective scan, dual-chain units ----
// Block = (b,e): 512 threads = 16 units of 32 lanes; unit u owns chunks u and
// u+16 with two INDEPENDENT interleaved chains (2x ILP on exp->fma, 2x MLP).
// Grid 768 = exactly 3 blocks/CU (launch_bounds(512,6)): single-round residency.
__global__ __launch_bounds__(512, 6) void scan_fused(
    const float* __restrict__ dT,
    const float* __restrict__ xT,
    const float* __restrict__ zT,     // silu(z)
    const float* __restrict__ Bi4,    // (B,L/4,32,4)
    const float* __restrict__ Ci4,    // (B,L/4,32,4)
    const float* __restrict__ CT,     // (B,32,L)
    const float* __restrict__ A_log,  // (48,32)
    const float* __restrict__ Dw,     // (48)
    float* __restrict__ ygT)          // (B,48,L)
{
    __shared__ float2 sPH[SNC][32];    // (P_chunk, h_end)
    __shared__ float2 sACa[SNC][32];   // (Ac, carry)
    __shared__ float  sYL[SNC][SCS];   // local y (incl. D*x)
    __shared__ float  sS [SNC][SCS];   // delta prefix within chunk

    const int tid = threadIdx.x;
    const int n = tid & 31;
    const int cA = tid >> 5;           // chunk 0..15
    const int cB = cA + 16;            // chunk 16..31
    const int b = blockIdx.x / 48;
    const int e = blockIdx.x % 48;

    const float Ac = -__expf(A_log[e*NST + n]);
    const float Dc = Dw[e];

    const size_t ebA = ((size_t)b*48 + e)*LL + cA*SCS;
    const size_t ebB = ((size_t)b*48 + e)*LL + cB*SCS;
    const float4* dpA = (const float4*)(dT + ebA);
    const float4* xpA = (const float4*)(xT + ebA);
    const float4* dpB = (const float4*)(dT + ebB);
    const float4* xpB = (const float4*)(xT + ebB);
    const float4* bpA = (const float4*)Bi4 + ((size_t)b*(LL/4) + cA*(SCS/4))*32 + n;
    const float4* cpA = (const float4*)Ci4 + ((size_t)b*(LL/4) + cA*(SCS/4))*32 + n;
    const float4* bpB = (const float4*)Bi4 + ((size_t)b*(LL/4) + cB*(SCS/4))*32 + n;
    const float4* cpB = (const float4*)Ci4 + ((size_t)b*(LL/4) + cB*(SCS/4))*32 + n;

    float hA = 0.f, SA = 0.f;
    float hB = 0.f, SB = 0.f;

    // ---- phase A: two independent chains interleaved ----
    #pragma unroll
    for (int q = 0; q < SCS/4; ++q) {
        float4 dA4 = dpA[q], xA4 = xpA[q];
        float4 dB4 = dpB[q], xB4 = xpB[q];
        float4 bA4 = bpA[q*32], cA4 = cpA[q*32];
        float4 bB4 = bpB[q*32], cB4 = cpB[q*32];
        float pA0, pA1, pA2, pA3, pB0, pB1, pB2, pB3;
        hA = fmaf(__expf(dA4.x*Ac), hA, dA4.x*xA4.x*bA4.x); pA0 = hA*cA4.x;
        hB = fmaf(__expf(dB4.x*Ac), hB, dB4.x*xB4.x*bB4.x); pB0 = hB*cB4.x;
        hA = fmaf(__expf(dA4.y*Ac), hA, dA4.y*xA4.y*bA4.y); pA1 = hA*cA4.y;
        hB = fmaf(__expf(dB4.y*Ac), hB, dB4.y*xB4.y*bB4.y); pB1 = hB*cB4.y;
        hA = fmaf(__expf(dA4.z*Ac), hA, dA4.z*xA4.z*bA4.z); pA2 = hA*cA4.z;
        hB = fmaf(__expf(dB4.z*Ac), hB, dB4.z*xB4.z*bB4.z); pB2 = hB*cB4.z;
        hA = fmaf(__expf(dA4.w*Ac), hA, dA4.w*xA4.w*bA4.w); pA3 = hA*cA4.w;
        hB = fmaf(__expf(dB4.w*Ac), hB, dB4.w*xB4.w*bB4.w); pB3 = hB*cB4.w;
        float sA0 = SA + dA4.x, sA1 = sA0 + dA4.y, sA2 = sA1 + dA4.z, sA3 = sA2 + dA4.w;
        float sB0 = SB + dB4.x, sB1 = sB0 + dB4.y, sB2 = sB1 + dB4.z, sB3 = sB2 + dB4.w;
        SA = sA3; SB = sB3;
        if (n == 0) {
            *(float4*)&sS[cA][4*q] = make_float4(sA0, sA1, sA2, sA3);
            *(float4*)&sS[cB][4*q] = make_float4(sB0, sB1, sB2, sB3);
        }
        // scattered 9-shfl butterfly, chunk A
        {
            float q0 = pA0 + __shfl_xor(pA0, 16);
            float q1 = pA1 + __shfl_xor(pA1, 16);
            float q2 = pA2 + __shfl_xor(pA2, 16);
            float q3 = pA3 + __shfl_xor(pA3, 16);
            float m01 = (n & 16) ? q1 : q0;
            float m23 = (n & 16) ? q3 : q2;
            m01 += __shfl_xor(m01, 8);
            m23 += __shfl_xor(m23, 8);
            float mm = (n & 8) ? m23 : m01;
            mm += __shfl_xor(mm, 4);
            mm += __shfl_xor(mm, 2);
            mm += __shfl_xor(mm, 1);
            if ((n & 7) == 0) {
                int vidx = ((n >> 4) & 1) | (((n >> 3) & 1) << 1);
                float xv = (vidx & 2) ? ((vidx & 1) ? xA4.w : xA4.z)
                                      : ((vidx & 1) ? xA4.y : xA4.x);
                sYL[cA][4*q + vidx] = fmaf(Dc, xv, mm);
            }
        }
        // scattered 9-shfl butterfly, chunk B
        {
            float q0 = pB0 + __shfl_xor(pB0, 16);
            float q1 = pB1 + __shfl_xor(pB1, 16);
            float q2 = pB2 + __shfl_xor(pB2, 16);
            float q3 = pB3 + __shfl_xor(pB3, 16);
            float m01 = (n & 16) ? q1 : q0;
            float m23 = (n & 16) ? q3 : q2;
            m01 += __shfl_xor(m01, 8);
            m23 += __shfl_xor(m23, 8);
            float mm = (n & 8) ? m23 : m01;
            mm += __shfl_xor(mm, 4);
            mm += __shfl_xor(mm, 2);
            mm += __shfl_xor(mm, 1);
            if ((n & 7) == 0) {
                int vidx = ((n >> 4) & 1) | (((n >> 3) & 1) << 1);
                float xv = (vidx & 2) ? ((vidx & 1) ? xB4.w : xB4.z)
                                      : ((vidx & 1) ? xB4.y : xB4.x);
                sYL[cB][4*q + vidx] = fmaf(Dc, xv, mm);
            }
        }
    }
    sPH[cA][n] = make_float2(__expf(Ac*SA), hA);
    sPH[cB][n] = make_float2(__expf(Ac*SB), hB);
    __syncthreads();

    // ---- phase B: carry scan over 32 chunks (one 32-lane unit, batched) ----
    if (tid < 32) {
        float acc = 0.f;
        #pragma unroll
        for (int batch = 0; batch < 4; ++batch) {
            float2 v[8];
            #pragma unroll
            for (int k = 0; k < 8; ++k) v[k] = sPH[batch*8+k][tid];
            #pragma unroll
            for (int k = 0; k < 8; ++k) {
                sACa[batch*8+k][tid] = make_float2(Ac, acc);
                acc = fmaf(v[k].x, acc, v[k].y);
            }
        }
    }
    __syncthreads();

    // ---- phase C: thread = (chunk, t), 2 rounds; coalesced CT reads ----
    #pragma unroll
    for (int r = 0; r < 2; ++r) {
        const int c2 = (tid >> 5) + 16*r;
        const int t = tid & 31;
        const float St = sS[c2][t];
        const float yl = sYL[c2][t];
        const float* ctp = CT + (size_t)b*32*LL + c2*SCS + t;
        float corr = 0.f;
        #pragma unroll
        for (int n2 = 0; n2 < 32; ++n2) {
            float2 w = sACa[c2][n2];
            corr = fmaf(ctp[(size_t)n2*LL] * __expf(w.x*St), w.y, corr);
        }
        const size_t o = ((size_t)b*48 + e)*LL + c2*SCS + t;
        ygT[o] = (yl + corr) * zT[o];
    }
}

// ---- head ----
__global__ __launch_bounds__(1024) void head_kernel(
    const float* __restrict__ ygT,
    const float* __restrict__ fcw, const float* __restrict__ fcb,
    const float* __restrict__ clw, const float* __restrict__ clb,
    const float* __restrict__ rgw, const float* __restrict__ rgb,
    float* __restrict__ out)
{
    __shared__ float s_h[BB*48];
    __shared__ float s_f[BB*48];
    const int tid = threadIdx.x;
    const int b = tid >> 6, j = tid & 63;
    if (j < 48) s_h[b*48+j] = ygT[((size_t)b*48 + j)*LL + (LL-1)];
    __syncthreads();
    if (j < 48) {
        float acc = fcb[j];
        for (int k = 0; k < 48; ++k) acc += s_h[b*48+k]*fcw[k*48+j];
        s_f[b*48+j] = fmaxf(acc, 0.f);
    }
    __syncthreads();
    if (j < NCLS) {
        float acc = clb[j];
        for (int k = 0; k < 48; ++k) acc += s_f[b*48+k]*clw[k*NCLS+j];
        out[b*NCLS + j] = acc;
    }
    if (j == NCLS) {
        float acc = rgb[0];
        for (int k = 0; k < 48; ++k) acc += s_f[b*48+k]*rgw[k];
        out[BB*NCLS + b] = acc;
    }
}

extern "C" void kernel_launch(void* const* d_in, const int* in_sizes, int n_in,
                              void* d_out, int out_size, void* d_ws, size_t ws_size,
                              hipStream_t stream)
{
    const float* x     = (const float*)d_in[0];
    const float* ipw   = (const float*)d_in[1];
    const float* cw    = (const float*)d_in[2];
    const float* cb    = (const float*)d_in[3];
    const float* xpw   = (const float*)d_in[4];
    const float* dtw   = (const float*)d_in[5];
    const float* dtb   = (const float*)d_in[6];
    const float* A_log = (const float*)d_in[7];
    const float* Dw    = (const float*)d_in[8];
    const float* nw    = (const float*)d_in[9];
    const float* opw   = (const float*)d_in[10];
    const float* fcw   = (const float*)d_in[11];
    const float* fcb   = (const float*)d_in[12];
    const float* clw   = (const float*)d_in[13];
    const float* clb   = (const float*)d_in[14];
    const float* rgw   = (const float*)d_in[15];
    const float* rgb   = (const float*)d_in[16];
    float* out = (float*)d_out;

    float* ws = (float*)d_ws;
    const size_t BL = (size_t)BB*LL;
    float* xT  = ws;
    float* zT  = xT  + BL*48;
    float* dT  = zT  + BL*48;
    float* Bi4 = dT  + BL*48;
    float* Ci4 = Bi4 + BL*32;
    float* CT  = Ci4 + BL*32;
    float* ygT = CT  + BL*32;

    const dim3 preGrid(BB*16), preBlk(PBT);
    const dim3 scanGrid(BB*48), scanBlk(512);

    // ---- layer 0 ----
    pre_kernel<0><<<preGrid, preBlk, 0, stream>>>(
        x, nullptr, nullptr, ipw, nw, cw, cb, xpw, dtw, dtb,
        xT, zT, dT, Bi4, Ci4, CT);
    scan_fused<<<scanGrid, scanBlk, 0, stream>>>(
        dT, xT, zT, Bi4, Ci4, CT, A_log, Dw, ygT);

    // ---- layer 1 ----
    pre_kernel<1><<<preGrid, preBlk, 0, stream>>>(
        x, ygT, opw, ipw + 576, nw + 6, cw + 768, cb + 48,
        xpw + 3120, dtw + 48, dtb + 48,
        xT, zT, dT, Bi4, Ci4, CT);
    scan_fused<<<scanGrid, scanBlk, 0, stream>>>(
        dT, xT, zT, Bi4, Ci4, CT, A_log + 1536, Dw + 48, ygT);

    head_kernel<<<dim3(1), dim3(1024), 0, stream>>>(
        ygT, fcw, fcb, clw, clb, rgw, rgb, out);
}

// Round 16
// 169.496 us; speedup vs baseline: 1.0071x; 1.0071x over previous
//
#include <hip/hip_runtime.h>
#include <math.h>

#define BB 16
#define LL 1024
#define DM 6
#define NST 32
#define DCONVK 16
#define NCLS 4
#define CH 64    // positions per pre-kernel block
#define HALO 15
#define ROWS (CH + HALO)   // 79
#define PBT 1024           // pre block threads
#define SNC 32   // scan chunks per block
#define SCS 32   // scan chunk length (SNC*SCS = LL)

__device__ __forceinline__ float softplus_f(float x) {
    return fmaxf(x, 0.f) + log1pf(expf(-fabsf(x)));
}
__device__ __forceinline__ float silu_f(float x) {
    return x / (1.f + __expf(-x));
}

// Fused: [MODE0: rmsnorm(x)] / [MODE1: ygT@opw + x residual -> rmsnorm]
//        -> in_proj -> split -> causal dwconv+silu -> x_proj -> softplus(delta)
// Outputs: xT/dT (B,48,L); zT = silu(z) (B,48,L);
//          Bi4/Ci4 packed (B,L/4,32,4); CT (B,32,L).
// LDS: s_pp / s_raw / s_bc are temporally disjoint -> unioned in s_un.
template<int MODE>
__global__ __launch_bounds__(PBT) void pre_kernel(
    const float* __restrict__ hin,     // x (B,L,6): MODE0 input / MODE1 residual
    const float* __restrict__ ygT_in,  // MODE1: (B,48,L)
    const float* __restrict__ opw,     // MODE1: (48,6)
    const float* __restrict__ ipw,     // (6,96)
    const float* __restrict__ nw,      // (6)
    const float* __restrict__ cw,      // (48,16)
    const float* __restrict__ cb,      // (48)
    const float* __restrict__ xpw,     // (48,65)
    const float* __restrict__ dtw,     // (48)
    const float* __restrict__ dtb,     // (48)
    float* __restrict__ xT,            // (B,48,L)
    float* __restrict__ zT,            // (B,48,L)  silu-applied
    float* __restrict__ dT,            // (B,48,L)
    float* __restrict__ Bi4,           // (B,L/4,32,4)
    float* __restrict__ Ci4,           // (B,L/4,32,4)
    float* __restrict__ CT)            // (B,32,L)
{
    __shared__ float s_un[ROWS*49 > 64*(CH+1) ? ROWS*49 : 64*(CH+1)];
    __shared__ float s_ipw[6*96];
    __shared__ float s_nw[8];
    __shared__ float s_cw[48*DCONVK];
    __shared__ float s_cb[48];
    __shared__ float s_xpw[48*65];
    __shared__ float s_dtw[48];
    __shared__ float s_dtb[48];
    __shared__ float s_opw[48*6];
    __shared__ float s_u[ROWS*7];
    __shared__ float s_xsT[48*CH];        // [c][p] channel-major
    __shared__ float s_dlt[CH];

    float* s_pp  = s_un;   // MODE1 phase 0: (ROWS,8,6)
    float* s_raw = s_un;   // phase 1-2: (ROWS,49)
    float* s_bc  = s_un;   // phase 3-3b: (64, CH+1)

    const int tid = threadIdx.x;
    const int b  = blockIdx.x >> 4;
    const int l0 = (blockIdx.x & 15) * CH;

    for (int i = tid; i < 6*96; i += PBT) s_ipw[i] = ipw[i];
    if (tid < 6) s_nw[tid] = nw[tid];
    if (tid < 48*DCONVK) s_cw[tid] = cw[tid];
    if (tid < 48) s_cb[tid] = cb[tid];
    for (int i = tid; i < 48*65; i += PBT) s_xpw[i] = xpw[i];
    if (tid < 48) { s_dtw[tid] = dtw[tid]; s_dtb[tid] = dtb[tid]; }
    if (MODE == 1) { if (tid < 48*6) s_opw[tid] = opw[tid]; }
    __syncthreads();

    // ---- phase 0: produce s_u (normalized rows l0-15 .. l0+CH-1) ----
    if (MODE == 0) {
        if (tid < ROWS) {
            int l = l0 - HALO + tid;
            float u[DM];
            if (l >= 0) {
                float ss = 0.f;
                const float* hp = hin + ((size_t)b*LL + l)*DM;
                #pragma unroll
                for (int d = 0; d < DM; ++d) { u[d] = hp[d]; ss += u[d]*u[d]; }
                float sc = rsqrtf(ss * (1.f/DM) + 1e-5f);
                #pragma unroll
                for (int d = 0; d < DM; ++d) u[d] *= sc * s_nw[d];
            } else {
                #pragma unroll
                for (int d = 0; d < DM; ++d) u[d] = 0.f;
            }
            #pragma unroll
            for (int d = 0; d < DM; ++d) s_u[tid*7+d] = u[d];
        }
        __syncthreads();
    } else {
        const int g = tid >> 7, t = tid & 127;   // 8 groups x 128 rows
        if (t < ROWS) {
            int l = l0 - HALO + t;
            float pacc[DM] = {0,0,0,0,0,0};
            if (l >= 0) {
                for (int e = g*6; e < g*6 + 6; ++e) {
                    float v = ygT_in[((size_t)b*48 + e)*LL + l];
                    #pragma unroll
                    for (int d = 0; d < DM; ++d) pacc[d] += v * s_opw[e*DM+d];
                }
            }
            #pragma unroll
            for (int d = 0; d < DM; ++d) s_pp[(t*8+g)*DM+d] = pacc[d];
        }
        __syncthreads();
        float u[DM]; float ss = 0.f;
        if (tid < ROWS) {
            int l = l0 - HALO + tid;
            if (l >= 0) {
                const float* xr = hin + ((size_t)b*LL + l)*DM;
                #pragma unroll
                for (int d = 0; d < DM; ++d) {
                    float hv = xr[d];
                    #pragma unroll
                    for (int g2 = 0; g2 < 8; ++g2) hv += s_pp[(tid*8+g2)*DM+d];
                    u[d] = hv; ss += hv*hv;
                }
                float sc = rsqrtf(ss * (1.f/DM) + 1e-5f);
                #pragma unroll
                for (int d = 0; d < DM; ++d) u[d] *= sc * s_nw[d];
            } else {
                #pragma unroll
                for (int d = 0; d < DM; ++d) u[d] = 0.f;
            }
        }
        __syncthreads();   // s_pp dead before s_raw written (same memory)
        if (tid < ROWS) {
            #pragma unroll
            for (int d = 0; d < DM; ++d) s_u[tid*7+d] = u[d];
        }
        __syncthreads();
    }

    // ---- phase 1: in_proj (96 cols x ROWS rows); z gets silu applied ----
    for (int i = tid; i < 96*ROWS; i += PBT) {
        int j = i / ROWS, t = i - j*ROWS;
        float acc = 0.f;
        #pragma unroll
        for (int d = 0; d < DM; ++d) acc += s_u[t*7+d]*s_ipw[d*96+j];
        if (j < 48) s_raw[t*49+j] = acc;
        else if (t >= HALO)
            zT[((size_t)b*48 + (j-48))*LL + (l0 - HALO + t)] = silu_f(acc);
    }
    __syncthreads();

    // ---- phase 2: depthwise causal conv (K=16) + silu ----
    for (int o = tid; o < 48*CH; o += PBT) {
        int c = o >> 6, p = o & 63;
        float acc = s_cb[c];
        #pragma unroll
        for (int k = 0; k < DCONVK; ++k)
            acc += s_raw[(p+k)*49 + c] * s_cw[c*DCONVK + k];
        float v = silu_f(acc);
        s_xsT[c*CH + p] = v;
        xT[((size_t)b*48 + c)*LL + l0 + p] = v;
    }
    __syncthreads();   // s_raw dead before s_bc written (same memory)

    // ---- phase 3: x_proj. thread = (col j:64, pos-group g:16), 4 pos each ----
    {
        const int j = tid >> 4, g = tid & 15;
        float a0=0,a1=0,a2=0,a3=0;
        for (int e = 0; e < 48; ++e) {
            float4 xv = *(const float4*)&s_xsT[e*CH + 4*g];
            float w = s_xpw[e*65 + 1 + j];
            a0 = fmaf(xv.x, w, a0); a1 = fmaf(xv.y, w, a1);
            a2 = fmaf(xv.z, w, a2); a3 = fmaf(xv.w, w, a3);
        }
        s_bc[j*(CH+1) + 4*g+0] = a0; s_bc[j*(CH+1) + 4*g+1] = a1;
        s_bc[j*(CH+1) + 4*g+2] = a2; s_bc[j*(CH+1) + 4*g+3] = a3;
    }
    if (tid < CH) {
        float acc = 0.f;
        for (int e = 0; e < 48; ++e) acc += s_xsT[e*CH + tid]*s_xpw[e*65];
        s_dlt[tid] = acc;
    }
    __syncthreads();

    // ---- phase 3b: write B/C packed (B,L/4,32,4) + C transposed ----
    {   // 2*(CH/4)*32 = 1024 items, exactly one per thread
        int o = tid;
        int which = o >> 9;                 // 0:B 1:C
        int lg = (o >> 5) & (CH/4 - 1), n = o & 31;
        const float* src = &s_bc[(which*32 + n)*(CH+1) + 4*lg];
        float4 v = make_float4(src[0], src[1], src[2], src[3]);
        float4* dst = (float4*)(which ? Ci4 : Bi4);
        dst[((size_t)b*(LL/4) + (l0/4 + lg))*32 + n] = v;
    }
    for (int o = tid; o < 32*CH; o += PBT) {
        int n = o >> 6, l = o & 63;
        CT[((size_t)b*32 + n)*LL + l0 + l] = s_bc[(32+n)*(CH+1) + l];
    }

    // ---- phase 4: delta = softplus(dlt*dt_w + dt_b), transposed write ----
    for (int o = tid; o < 48*CH; o += PBT) {
        int e = o >> 6, p = o & 63;
        float xv = s_dlt[p]*s_dtw[e] + s_dtb[e];
        dT[((size_t)b*48 + e)*LL + l0 + p] = softplus_f(xv);
    }
}

// ---- fused selective scan (R14 best) ----
__global__ __launch_bounds__(1024, 8) void scan_fused(
    const float* __restrict__ dT,
    const float* __restrict__ xT,
    const float* __restrict__ zT,     // silu(z)
    const float* __restrict__ Bi4,    // (B,L/4,32,4)
    const float* __restrict__ Ci4,    // (B,L/4,32,4)
    const float* __restrict__ CT,     // (B,32,L)
    const float* __restrict__ A_log,  // (48,32)
    const float* __restrict__ Dw,     // (48)
    float* __restrict__ ygT)          // (B,48,L)
{
    __shared__ float2 sPH[SNC][32];    // (P_chunk, h_end)
    __shared__ float2 sACa[SNC][32];   // (Ac, carry)
    __shared__ float  sYL[SNC][SCS];   // local y (incl. D*x)
    __shared__ float  sS [SNC][SCS];   // delta prefix within chunk

    const int tid = threadIdx.x;
    const int lane = tid & 63;
    const int ch = lane >> 5, n = lane & 31;
    const int c = ((tid >> 6) << 1) | ch;   // chunk 0..31
    const int b = blockIdx.x / 48;
    const int e = blockIdx.x % 48;

    const float Ac = -__expf(A_log[e*NST + n]);
    const float Dc = Dw[e];

    const size_t eb = ((size_t)b*48 + e)*LL + c*SCS;
    const float4* dp = (const float4*)(dT + eb);
    const float4* xp = (const float4*)(xT + eb);
    const float4* bp4 = (const float4*)Bi4 + ((size_t)b*(LL/4) + c*(SCS/4))*32 + n;
    const float4* cp4 = (const float4*)Ci4 + ((size_t)b*(LL/4) + c*(SCS/4))*32 + n;

    float h = 0.f, S = 0.f;

    // ---- phase A ----
    #pragma unroll
    for (int q = 0; q < SCS/4; ++q) {
        float4 d4 = dp[q], x4 = xp[q];
        float4 b4 = bp4[q*32];
        float4 c4 = cp4[q*32];
        float p0, p1, p2, p3;
        h = fmaf(__expf(d4.x*Ac), h, d4.x*x4.x*b4.x); p0 = h*c4.x;
        h = fmaf(__expf(d4.y*Ac), h, d4.y*x4.y*b4.y); p1 = h*c4.y;
        h = fmaf(__expf(d4.z*Ac), h, d4.z*x4.z*b4.z); p2 = h*c4.z;
        h = fmaf(__expf(d4.w*Ac), h, d4.w*x4.w*b4.w); p3 = h*c4.w;
        float s0 = S + d4.x, s1 = s0 + d4.y, s2 = s1 + d4.z, s3 = s2 + d4.w;
        S = s3;
        if (n == 0) *(float4*)&sS[c][4*q] = make_float4(s0, s1, s2, s3);
        float q0 = p0 + __shfl_xor(p0, 16);
        float q1 = p1 + __shfl_xor(p1, 16);
        float q2 = p2 + __shfl_xor(p2, 16);
        float q3 = p3 + __shfl_xor(p3, 16);
        float m01 = (n & 16) ? q1 : q0;
        float m23 = (n & 16) ? q3 : q2;
        m01 += __shfl_xor(m01, 8);
        m23 += __shfl_xor(m23, 8);
        float mm = (n & 8) ? m23 : m01;
        mm += __shfl_xor(mm, 4);
        mm += __shfl_xor(mm, 2);
        mm += __shfl_xor(mm, 1);
        if ((n & 7) == 0) {
            int vidx = ((n >> 4) & 1) | (((n >> 3) & 1) << 1);
            float xv = (vidx & 2) ? ((vidx & 1) ? x4.w : x4.z)
                                  : ((vidx & 1) ? x4.y : x4.x);
            sYL[c][4*q + vidx] = fmaf(Dc, xv, mm);
        }
    }
    sPH[c][n] = make_float2(__expf(Ac*S), h);
    __syncthreads();

    // ---- phase B: carry scan over 32 chunks (one 32-lane unit, batched) ----
    if (tid < 32) {
        float acc = 0.f;
        #pragma unroll
        for (int batch = 0; batch < 4; ++batch) {
            float2 v[8];
            #pragma unroll
            for (int k = 0; k < 8; ++k) v[k] = sPH[batch*8+k][tid];
            #pragma unroll
            for (int k = 0; k < 8; ++k) {
                sACa[batch*8+k][tid] = make_float2(Ac, acc);
                acc = fmaf(v[k].x, acc, v[k].y);
            }
        }
    }
    __syncthreads();

    // ---- phase C: thread = (chunk, t); coalesced CT reads ----
    {
        const int c2 = tid >> 5;
        const int t = tid & 31;
        const float St = sS[c2][t];
        const float yl = sYL[c2][t];
        const float* ctp = CT + (size_t)b*32*LL + c2*SCS + t;
        float corr = 0.f;
        #pragma unroll
        for (int n2 = 0; n2 < 32; ++n2) {
            float2 w = sACa[c2][n2];
            corr = fmaf(ctp[(size_t)n2*LL] * __expf(w.x*St), w.y, corr);
        }
        const size_t o = ((size_t)b*48 + e)*LL + c2*SCS + t;
        ygT[o] = (yl + corr) * zT[o];
    }
}

// ---- head ----
__global__ __launch_bounds__(1024) void head_kernel(
    const float* __restrict__ ygT,
    const float* __restrict__ fcw, const float* __restrict__ fcb,
    const float* __restrict__ clw, const float* __restrict__ clb,
    const float* __restrict__ rgw, const float* __restrict__ rgb,
    float* __restrict__ out)
{
    __shared__ float s_h[BB*48];
    __shared__ float s_f[BB*48];
    const int tid = threadIdx.x;
    const int b = tid >> 6, j = tid & 63;
    if (j < 48) s_h[b*48+j] = ygT[((size_t)b*48 + j)*LL + (LL-1)];
    __syncthreads();
    if (j < 48) {
        float acc = fcb[j];
        for (int k = 0; k < 48; ++k) acc += s_h[b*48+k]*fcw[k*48+j];
        s_f[b*48+j] = fmaxf(acc, 0.f);
    }
    __syncthreads();
    if (j < NCLS) {
        float acc = clb[j];
        for (int k = 0; k < 48; ++k) acc += s_f[b*48+k]*clw[k*NCLS+j];
        out[b*NCLS + j] = acc;
    }
    if (j == NCLS) {
        float acc = rgb[0];
        for (int k = 0; k < 48; ++k) acc += s_f[b*48+k]*rgw[k];
        out[BB*NCLS + b] = acc;
    }
}

extern "C" void kernel_launch(void* const* d_in, const int* in_sizes, int n_in,
                              void* d_out, int out_size, void* d_ws, size_t ws_size,
                              hipStream_t stream)
{
    const float* x     = (const float*)d_in[0];
    const float* ipw   = (const float*)d_in[1];
    const float* cw    = (const float*)d_in[2];
    const float* cb    = (const float*)d_in[3];
    const float* xpw   = (const float*)d_in[4];
    const float* dtw   = (const float*)d_in[5];
    const float* dtb   = (const float*)d_in[6];
    const float* A_log = (const float*)d_in[7];
    const float* Dw    = (const float*)d_in[8];
    const float* nw    = (const float*)d_in[9];
    const float* opw   = (const float*)d_in[10];
    const float* fcw   = (const float*)d_in[11];
    const float* fcb   = (const float*)d_in[12];
    const float* clw   = (const float*)d_in[13];
    const float* clb   = (const float*)d_in[14];
    const float* rgw   = (const float*)d_in[15];
    const float* rgb   = (const float*)d_in[16];
    float* out = (float*)d_out;

    float* ws = (float*)d_ws;
    const size_t BL = (size_t)BB*LL;
    float* xT  = ws;
    float* zT  = xT  + BL*48;
    float* dT  = zT  + BL*48;
    float* Bi4 = dT  + BL*48;
    float* Ci4 = Bi4 + BL*32;
    float* CT  = Ci4 + BL*32;
    float* ygT = CT  + BL*32;

    const dim3 preGrid(BB*16), preBlk(PBT);
    const dim3 scanGrid(BB*48), scanBlk(1024);

    // ---- layer 0 ----
    pre_kernel<0><<<preGrid, preBlk, 0, stream>>>(
        x, nullptr, nullptr, ipw, nw, cw, cb, xpw, dtw, dtb,
        xT, zT, dT, Bi4, Ci4, CT);
    scan_fused<<<scanGrid, scanBlk, 0, stream>>>(
        dT, xT, zT, Bi4, Ci4, CT, A_log, Dw, ygT);

    // ---- layer 1 ----
    pre_kernel<1><<<preGrid, preBlk, 0, stream>>>(
        x, ygT, opw, ipw + 576, nw + 6, cw + 768, cb + 48,
        xpw + 3120, dtw + 48, dtb + 48,
        xT, zT, dT, Bi4, Ci4, CT);
    scan_fused<<<scanGrid, scanBlk, 0, stream>>>(
        dT, xT, zT, Bi4, Ci4, CT, A_log + 1536, Dw + 48, ygT);

    head_kernel<<<dim3(1), dim3(1024), 0, stream>>>(
        ygT, fcw, fcb, clw, clb, rgw, rgb, out);
}